// Round 8
// baseline (228.157 us; speedup 1.0000x reference)
//
#include <hip/hip_runtime.h>
#include <hip/hip_bf16.h>

// ---------------------------------------------------------------------------
// GCN: h = relu(gcnconv(x,W1,b1)); z = gcnconv(h,W2,b2); out[e]=dot(z[s],z[d])
// CSR build = bucketed counting sort, 4 kernels: hist(+bucket sums via
// atomics) -> rowscan(redundant bucket-sum scan folded in) -> reorder ->
// bucket_csr. All random writes land in block-owned windows.
// GEMM epilogue pre-scales rows by dis and packs to BF16 (gathered tables
// are 128B/row). Aggregation gathers with 8 lanes x 16B per edge-row and
// 8 edge-groups/wave, 2-deep unrolled -> up to 16 gathers in flight.
// Agg batches 64 edge indices per wave via LDS (ds_read broadcast is
// exec-mask safe; __shfl from tail-inactive lanes is NOT - R5 failure).
// ---------------------------------------------------------------------------

constexpr int NC = 512;      // edge chunks (= hist/reorder grid, 2 blocks/CU)
constexpr int NBPAD = 256;   // padded bucket count (>= nbk)
constexpr int BSHIFT = 8;    // 256 nodes per bucket

__device__ __forceinline__ unsigned short f2bf(float f) {   // RNE
    unsigned u = __float_as_uint(f);
    return (unsigned short)((u + 0x7FFF + ((u >> 16) & 1)) >> 16);
}
__device__ __forceinline__ float bflo(unsigned u) { return __uint_as_float(u << 16); }
__device__ __forceinline__ float bfhi(unsigned u) { return __uint_as_float(u & 0xFFFF0000u); }

__device__ __forceinline__ void bfacc8(float* acc, uint4 q) {
    acc[0] += bflo(q.x); acc[1] += bfhi(q.x);
    acc[2] += bflo(q.y); acc[3] += bfhi(q.y);
    acc[4] += bflo(q.z); acc[5] += bfhi(q.z);
    acc[6] += bflo(q.w); acc[7] += bfhi(q.w);
}

// hist[bucket][chunk] counts + bucket totals (bsums) via global atomics.
__global__ __launch_bounds__(256) void hist_kernel(const int* __restrict__ col,
                                                   int* __restrict__ hist,
                                                   int* __restrict__ bsums, int E, int CE) {
    __shared__ int hl[NBPAD];
    const int t = threadIdx.x, c = blockIdx.x;
    hl[t] = 0;
    __syncthreads();
    const int s = c * CE, e = min(E, s + CE);
    for (int i = s + t; i < e; i += 256) atomicAdd(&hl[col[i] >> BSHIFT], 1);
    __syncthreads();
    const int v = hl[t];
    hist[t * NC + c] = v;            // bucket-major
    if (v) atomicAdd(&bsums[t], v);  // bucket totals
}

// Per bucket: redundant exclusive scan of bucket sums (256 ints) for the
// bucket base, then exclusive scan of the bucket's 512 chunk counts
// (2 per thread), writing global offsets back into hist.
__global__ __launch_bounds__(256) void rowscan_kernel(int* __restrict__ hist,
                                                      const int* __restrict__ bsums) {
    __shared__ int sb[256];
    __shared__ int sc[256];
    const int t = threadIdx.x, b = blockIdx.x;
    sb[t] = bsums[t];
    __syncthreads();
    for (int off = 1; off < 256; off <<= 1) {
        int u = (t >= off) ? sb[t - off] : 0;
        __syncthreads();
        sb[t] += u;
        __syncthreads();
    }
    const int base = (b == 0) ? 0 : sb[b - 1];
    const int i0 = b * NC + 2 * t;
    const int a0 = hist[i0], a1 = hist[i0 + 1];
    const int ps = a0 + a1;
    sc[t] = ps;
    __syncthreads();
    for (int off = 1; off < 256; off <<= 1) {
        int u = (t >= off) ? sc[t - off] : 0;
        __syncthreads();
        sc[t] += u;
        __syncthreads();
    }
    const int excl = sc[t] - ps;
    hist[i0] = base + excl;
    hist[i0 + 1] = base + excl + a0;
}

// Scatter (row,col) pairs into per-(bucket,chunk) contiguous runs of part[].
__global__ __launch_bounds__(256) void reorder_kernel(const int* __restrict__ row,
                                                      const int* __restrict__ col,
                                                      const int* __restrict__ hist,
                                                      int2* __restrict__ part, int E, int CE) {
    __shared__ int cur[NBPAD];
    const int t = threadIdx.x, c = blockIdx.x;
    cur[t] = hist[t * NC + c];
    __syncthreads();
    const int s = c * CE, e = min(E, s + CE);
    for (int i = s + t; i < e; i += 256) {
        const int r = row[i], cl = col[i];
        const int p = atomicAdd(&cur[cl >> BSHIFT], 1);
        part[p] = make_int2(r, cl);
    }
}

// One block per bucket: LDS degree count -> LDS scan -> offs/dis -> scatter
// rows into the bucket's private csr window.
__global__ __launch_bounds__(256) void bucket_csr_kernel(const int2* __restrict__ part,
                                                         const int* __restrict__ hist,
                                                         int* __restrict__ csr,
                                                         int* __restrict__ offs,
                                                         float* __restrict__ dis,
                                                         int N, int E, int nbk) {
    __shared__ int cnt[256];
    __shared__ int sc[256];
    const int t = threadIdx.x, b = blockIdx.x;
    const int base = b << BSHIFT;
    const int bstart = hist[b * NC];
    const int bend = (b + 1 < NBPAD) ? hist[(b + 1) * NC] : E;
    const int m = bend - bstart;
    cnt[t] = 0;
    __syncthreads();
    for (int i = t; i < m; i += 256) atomicAdd(&cnt[part[bstart + i].y - base], 1);
    __syncthreads();
    const int v = cnt[t];
    sc[t] = v;
    __syncthreads();
    for (int off = 1; off < 256; off <<= 1) {
        int u = (t >= off) ? sc[t - off] : 0;
        __syncthreads();
        sc[t] += u;
        __syncthreads();
    }
    const int excl = sc[t] - v;
    const int node = base + t;
    if (node < N) {
        offs[node] = bstart + excl;
        dis[node] = rsqrtf((float)(v + 1));   // +1 = self loop
    }
    sc[t] = excl;          // repurpose as scatter cursor
    __syncthreads();
    for (int i = t; i < m; i += 256) {
        const int2 ec = part[bstart + i];
        const int p = atomicAdd(&sc[ec.y - base], 1);
        csr[bstart + p] = ec.x;
    }
    if (b == nbk - 1 && t == 0) offs[N] = E;
}

// Y[N,64] (bf16) = rowscale[r] * (X[N,K] @ W[K,64]).
// Block = 256 thr = 16x16 grid; 4x4 register micro-tile; both operands in
// LDS (k-major); per k: 2 ds_read_b128 + 16 FMAs, no global loads in k-loop.
template <int K>
__global__ __launch_bounds__(256) void gemm_tile(const float* __restrict__ X,
                                                 const float* __restrict__ W,
                                                 const float* __restrict__ rowscale,
                                                 unsigned short* __restrict__ Y, int nrows) {
    __shared__ float sX[64 * 64];
    __shared__ float sW[64 * 64];
    const int tid = threadIdx.x;
    const int tx = tid & 15;         // col group
    const int ty = tid >> 4;         // row group
    const int rowbase = blockIdx.x * 64;

    float acc[16];
    #pragma unroll
    for (int i = 0; i < 16; ++i) acc[i] = 0.f;

    const int lr = tid & 63;         // loader row (0..63)
    const int lq = tid >> 6;         // loader k-quarter (16 k's each)
    int grow = rowbase + lr;
    if (grow >= nrows) grow = nrows - 1;   // clamp; stores are guarded
    const float* xrow = X + (long)grow * K;

    for (int kc = 0; kc < K; kc += 64) {
        if (kc) __syncthreads();
        #pragma unroll
        for (int i = 0; i < 4; ++i) {
            const int o = tid * 4 + i * 1024;
            *(float4*)&sW[o] = *(const float4*)&W[(long)kc * 64 + o];
        }
        #pragma unroll
        for (int t = 0; t < 4; ++t) {
            const int k = lq * 16 + t * 4;
            const float4 v = *(const float4*)&xrow[kc + k];
            sX[(k + 0) * 64 + lr] = v.x;
            sX[(k + 1) * 64 + lr] = v.y;
            sX[(k + 2) * 64 + lr] = v.z;
            sX[(k + 3) * 64 + lr] = v.w;
        }
        __syncthreads();
        #pragma unroll 4
        for (int k = 0; k < 64; ++k) {
            const float4 xv = *(const float4*)&sX[k * 64 + ty * 4];
            const float4 wv = *(const float4*)&sW[k * 64 + tx * 4];
            acc[0]  = fmaf(xv.x, wv.x, acc[0]);
            acc[1]  = fmaf(xv.x, wv.y, acc[1]);
            acc[2]  = fmaf(xv.x, wv.z, acc[2]);
            acc[3]  = fmaf(xv.x, wv.w, acc[3]);
            acc[4]  = fmaf(xv.y, wv.x, acc[4]);
            acc[5]  = fmaf(xv.y, wv.y, acc[5]);
            acc[6]  = fmaf(xv.y, wv.z, acc[6]);
            acc[7]  = fmaf(xv.y, wv.w, acc[7]);
            acc[8]  = fmaf(xv.z, wv.x, acc[8]);
            acc[9]  = fmaf(xv.z, wv.y, acc[9]);
            acc[10] = fmaf(xv.z, wv.z, acc[10]);
            acc[11] = fmaf(xv.z, wv.w, acc[11]);
            acc[12] = fmaf(xv.w, wv.x, acc[12]);
            acc[13] = fmaf(xv.w, wv.y, acc[13]);
            acc[14] = fmaf(xv.w, wv.z, acc[14]);
            acc[15] = fmaf(xv.w, wv.w, acc[15]);
        }
    }

    #pragma unroll
    for (int i = 0; i < 4; ++i) {
        const int orow = rowbase + ty * 4 + i;
        if (orow < nrows) {
            const float d = rowscale[orow];
            ushort4 ov;
            ov.x = f2bf(d * acc[i * 4 + 0]);
            ov.y = f2bf(d * acc[i * 4 + 1]);
            ov.z = f2bf(d * acc[i * 4 + 2]);
            ov.w = f2bf(d * acc[i * 4 + 3]);
            *(ushort4*)&Y[(long)orow * 64 + tx * 4] = ov;
        }
    }
}

// One wave per node, 8 groups of 8 lanes (lane fl owns feats fl*8..+7 as
// uint4 of 8 bf16). 8 edges in flight per wave, x2 with the 2-deep unroll.
// Batch: 64 edge indices coalesced into LDS; ds_read broadcast (exec-safe).
// OUT_BF16: agg1 -> fp32 h (dense, feeds gemm2); agg2 -> bf16 z (gathered).
template <bool RELU, bool OUT_BF16>
__global__ __launch_bounds__(256) void agg_kernel(const unsigned short* __restrict__ xs,
                                                  const int* __restrict__ csr,
                                                  const int* __restrict__ offs,
                                                  const float* __restrict__ dis,
                                                  const float* __restrict__ bias,
                                                  void* __restrict__ out, int n) {
    __shared__ int sidx[4][64];
    const int wv = threadIdx.x >> 6;
    const int lane = threadIdx.x & 63;
    const int grp = lane >> 3;       // 8 groups
    const int fl = lane & 7;         // 8 lanes: 16B each
    const int i = blockIdx.x * 4 + wv;
    if (i >= n) return;
    float acc[8];
    #pragma unroll
    for (int j = 0; j < 8; ++j) acc[j] = 0.f;
    if (grp == 0)    // self loop counted once (xs already = dis*xw)
        bfacc8(acc, *(const uint4*)&xs[(long)i * 64 + fl * 8]);
    const int s = offs[i];
    const int e = offs[i + 1];
    for (int jb = s; jb < e; jb += 64) {
        const int nb = min(64, e - jb);
        if (lane < nb) sidx[wv][lane] = csr[jb + lane];
        // same-wave DS ops are processed in order: reads below see the writes
        int u = grp;
        for (; u + 8 < nb; u += 16) {
            const int r0 = sidx[wv][u];
            const int r1 = sidx[wv][u + 8];
            const uint4 q0 = *(const uint4*)&xs[(long)r0 * 64 + fl * 8];
            const uint4 q1 = *(const uint4*)&xs[(long)r1 * 64 + fl * 8];
            bfacc8(acc, q0);
            bfacc8(acc, q1);
        }
        for (; u < nb; u += 8) {
            const int r0 = sidx[wv][u];
            bfacc8(acc, *(const uint4*)&xs[(long)r0 * 64 + fl * 8]);
        }
    }
    #pragma unroll
    for (int j = 0; j < 8; ++j) {
        acc[j] += __shfl_xor(acc[j], 8);
        acc[j] += __shfl_xor(acc[j], 16);
        acc[j] += __shfl_xor(acc[j], 32);
    }
    if (grp == 0) {
        const float di = dis[i];
        const float4 b0 = *(const float4*)&bias[fl * 8 + 0];
        const float4 b4 = *(const float4*)&bias[fl * 8 + 4];
        float o[8];
        o[0] = fmaf(acc[0], di, b0.x); o[1] = fmaf(acc[1], di, b0.y);
        o[2] = fmaf(acc[2], di, b0.z); o[3] = fmaf(acc[3], di, b0.w);
        o[4] = fmaf(acc[4], di, b4.x); o[5] = fmaf(acc[5], di, b4.y);
        o[6] = fmaf(acc[6], di, b4.z); o[7] = fmaf(acc[7], di, b4.w);
        if (RELU) {
            #pragma unroll
            for (int j = 0; j < 8; ++j) o[j] = fmaxf(o[j], 0.f);
        }
        if (OUT_BF16) {
            uint4 q;
            q.x = (unsigned)f2bf(o[0]) | ((unsigned)f2bf(o[1]) << 16);
            q.y = (unsigned)f2bf(o[2]) | ((unsigned)f2bf(o[3]) << 16);
            q.z = (unsigned)f2bf(o[4]) | ((unsigned)f2bf(o[5]) << 16);
            q.w = (unsigned)f2bf(o[6]) | ((unsigned)f2bf(o[7]) << 16);
            *(uint4*)&((unsigned short*)out)[(long)i * 64 + fl * 8] = q;
        } else {
            float* op = (float*)out + (long)i * 64 + fl * 8;
            *(float4*)&op[0] = make_float4(o[0], o[1], o[2], o[3]);
            *(float4*)&op[4] = make_float4(o[4], o[5], o[6], o[7]);
        }
    }
}

// 8 lanes per label edge (32 edges/wave): 16B bf16 gathers; 3-step xor reduce.
__global__ __launch_bounds__(256) void decode_kernel(const unsigned short* __restrict__ z,
                                                     const int* __restrict__ src,
                                                     const int* __restrict__ dst,
                                                     float* __restrict__ out, int L) {
    const int t = blockIdx.x * 256 + threadIdx.x;
    const int e = t >> 3;
    const int fl = t & 7;
    if (e >= L) return;
    const int s = src[e];
    const int d = dst[e];
    const uint4 qa = *(const uint4*)&z[(long)s * 64 + fl * 8];
    const uint4 qb = *(const uint4*)&z[(long)d * 64 + fl * 8];
    float p = bflo(qa.x) * bflo(qb.x) + bfhi(qa.x) * bfhi(qb.x)
            + bflo(qa.y) * bflo(qb.y) + bfhi(qa.y) * bfhi(qb.y)
            + bflo(qa.z) * bflo(qb.z) + bfhi(qa.z) * bfhi(qb.z)
            + bflo(qa.w) * bflo(qb.w) + bfhi(qa.w) * bfhi(qb.w);
    p += __shfl_xor(p, 4); p += __shfl_xor(p, 2); p += __shfl_xor(p, 1);
    if (fl == 0) out[e] = p;
}

extern "C" void kernel_launch(void* const* d_in, const int* in_sizes, int n_in,
                              void* d_out, int out_size, void* d_ws, size_t ws_size,
                              hipStream_t stream) {
    const float* x   = (const float*)d_in[0];
    const int*   ei  = (const int*)d_in[1];
    const int*   eli = (const int*)d_in[2];
    const float* W1  = (const float*)d_in[3];
    const float* b1  = (const float*)d_in[4];
    const float* W2  = (const float*)d_in[5];
    const float* b2  = (const float*)d_in[6];
    float* out = (float*)d_out;

    const int N = in_sizes[0] / 256;   // 50000 nodes (IN_CH = 256)
    const int E = in_sizes[1] / 2;     // 800000 edges
    const int L = in_sizes[2] / 2;     // 200000 label edges
    const int* row = ei;
    const int* col = ei + E;
    const int* src = eli;
    const int* dst = eli + L;

    char* w = (char*)d_ws;
    unsigned short* xs = (unsigned short*)w;  w += (size_t)N * 64 * 2;  // bf16 pre-agg feats
    float* h   = (float*)w;  w += (size_t)N * 64 * 4;                   // layer-1 output (fp32)
    unsigned short* z = (unsigned short*)w;  w += (size_t)N * 64 * 2;   // bf16 layer-2 output
    int*   csr = (int*)w;    w += (size_t)E * 4;        // sources sorted by target
    int*   offs = (int*)w;   w += (size_t)(N + 1) * 4;  // CSR offsets (N+1)
    float* dis = (float*)w;  w += (size_t)N * 4;        // rsqrt(deg+1)
    int2*  part = (int2*)w;  w += (size_t)E * 8;        // reorder staging (int2 per edge)
    // alias (dead before h is written):
    int*  hist  = (int*)h;                  // NBPAD*NC ints (512KB), consumed pre-agg1
    int*  bsums = hist + NBPAD * NC;        // 1KB, right after hist (still inside h)

    const int CE = (E + NC - 1) / NC;
    const int nbk = (N + (1 << BSHIFT) - 1) >> BSHIFT;   // 196 buckets

    hipMemsetAsync(bsums, 0, NBPAD * sizeof(int), stream);
    hist_kernel<<<NC, 256, 0, stream>>>(col, hist, bsums, E, CE);
    rowscan_kernel<<<NBPAD, 256, 0, stream>>>(hist, bsums);
    reorder_kernel<<<NC, 256, 0, stream>>>(row, col, hist, part, E, CE);
    bucket_csr_kernel<<<nbk, 256, 0, stream>>>(part, hist, csr, offs, dis, N, E, nbk);

    gemm_tile<256><<<(N + 63) / 64, 256, 0, stream>>>(x, W1, dis, xs, N);
    agg_kernel<true, false><<<(N + 3) / 4, 256, 0, stream>>>(xs, csr, offs, dis, b1, h, N);
    gemm_tile<64><<<(N + 63) / 64, 256, 0, stream>>>(h, W2, dis, xs, N);
    agg_kernel<false, true><<<(N + 3) / 4, 256, 0, stream>>>(xs, csr, offs, dis, b2, z, N);
    decode_kernel<<<(L * 8 + 255) / 256, 256, 0, stream>>>(z, src, dst, out, L);
}